// Round 2
// baseline (874.015 us; speedup 1.0000x reference)
//
#include <hip/hip_runtime.h>
#include <math.h>

#define N   12288
#define D   64
#define CAP 96   // max neighbors/row; Binomial(12288,0.002) mean 24.6, P(>=96) ~ 1e-30

#define CHUNKS      (N * (N / 4))        // 37,748,736 uint4 (16B) chunks of adj
#define SCAN_BLOCKS 2048
#define SCAN_UNROLL 8
#define SCAN_STRIDE (SCAN_BLOCKS * 256)  // 524,288 threads
#define SCAN_PASSES (CHUNKS / (SCAN_STRIDE * SCAN_UNROLL))  // exactly 9, no tail

typedef unsigned int uint4n __attribute__((ext_vector_type(4)));

__device__ __forceinline__ float wave_sum(float v) {
    #pragma unroll
    for (int m = 32; m >= 1; m >>= 1) v += __shfl_xor(v, m, 64);
    return v;
}
__device__ __forceinline__ float sigmoidf(float a) { return 1.0f / (1.0f + __expf(-a)); }

// K1: one wave per row: h = LL(x) kept in registers, then q (negated time) and k
// computed straight from register h. One dispatch for all three linears.
// Also zeroes the per-row neighbor counters for the scan kernel.
__global__ __launch_bounds__(256) void linear_kernel(
        const float* __restrict__ x,
        const float* __restrict__ W,  const float* __restrict__ b,  const float* __restrict__ scale,
        const float* __restrict__ Wq, const float* __restrict__ bq, const float* __restrict__ scale_q,
        const float* __restrict__ Wk, const float* __restrict__ bk, const float* __restrict__ scale_k,
        float* __restrict__ h, float* __restrict__ qm, float* __restrict__ kmat,
        int* __restrict__ cnt) {
    __shared__ float Wl [D * (D + 1)];   // +1 pad: 2-way bank alias (free)
    __shared__ float Wql[D * (D + 1)];
    __shared__ float Wkl[D * (D + 1)];

    const int tid  = threadIdx.x;
    const int lane = tid & 63;
    const int w    = tid >> 6;
    const int row  = blockIdx.x * 4 + w;

    if (tid < 4) cnt[blockIdx.x * 4 + tid] = 0;   // zero counters for scan_kernel

    for (int idx = tid; idx < D * D; idx += 256) {
        int d = idx >> 6, kk = idx & 63;
        Wl [d * (D + 1) + kk] = W [idx];
        Wql[d * (D + 1) + kk] = Wq[idx];
        Wkl[d * (D + 1) + kk] = Wk[idx];
    }
    __syncthreads();

    float hvv;
    {
        float xv  = x[row * D + lane];
        float acc = b[lane];
        const float* wr = &Wl[lane * (D + 1)];
        #pragma unroll
        for (int kk = 0; kk < D; ++kk)
            acc = fmaf(__shfl(xv, kk, 64), wr[kk], acc);
        float h0   = __shfl(acc, 0, 64);
        float time = __expf(scale[0]) * sigmoidf(h0) + 1.1f;
        float sq   = fmaxf(wave_sum((lane == 0) ? 0.0f : acc * acc), 1e-8f);
        float r    = sqrtf((time * time - 1.0f) / sq);
        hvv = (lane == 0) ? time : acc * r;
        h[row * D + lane] = hvv;
    }

    {
        float accq = bq[lane], acck = bk[lane];
        const float* wq = &Wql[lane * (D + 1)];
        const float* wk = &Wkl[lane * (D + 1)];
        #pragma unroll
        for (int kk = 0; kk < D; ++kk) {
            float xk = __shfl(hvv, kk, 64);
            accq = fmaf(xk, wq[kk], accq);
            acck = fmaf(xk, wk[kk], acck);
        }
        {
            float h0   = __shfl(accq, 0, 64);
            float time = __expf(scale_q[0]) * sigmoidf(h0) + 1.1f;
            float sq   = fmaxf(wave_sum((lane == 0) ? 0.0f : accq * accq), 1e-8f);
            float r    = sqrtf((time * time - 1.0f) / sq);
            qm[row * D + lane] = (lane == 0) ? -time : accq * r;
        }
        {
            float h0   = __shfl(acck, 0, 64);
            float time = __expf(scale_k[0]) * sigmoidf(h0) + 1.1f;
            float sq   = fmaxf(wave_sum((lane == 0) ? 0.0f : acck * acck), 1e-8f);
            float r    = sqrtf((time * time - 1.0f) / sq);
            kmat[row * D + lane] = (lane == 0) ? time : acck * r;
        }
    }
}

// K2a: pure-streaming scan of adj (604 MB, read-once). PLAIN loads — the NT
// hint capped the stream at ~1.6 TB/s across two different structures; the
// L2/L3 pollution it prevented is only ~9 MB of kmat/h re-fetch.
// Grid-stride, 8 independent 16B loads in flight per thread, no barriers.
// Nonzeros (~0.8% of chunks) take the rare path: global atomicAdd into
// per-row compact neighbor lists.
__global__ __launch_bounds__(256) void scan_kernel(
        const uint4n* __restrict__ adj4,
        int* __restrict__ cnt,
        int* __restrict__ cols) {
    const int idx0 = blockIdx.x * 256 + threadIdx.x;
    for (int p = 0; p < SCAN_PASSES; ++p) {
        const int g0 = idx0 + p * (SCAN_STRIDE * SCAN_UNROLL);
        uint4n v[SCAN_UNROLL];
        #pragma unroll
        for (int k = 0; k < SCAN_UNROLL; ++k)
            v[k] = adj4[g0 + k * SCAN_STRIDE];
        #pragma unroll
        for (int k = 0; k < SCAN_UNROLL; ++k) {
            uint4n vk = v[k];
            if ((vk.x | vk.y | vk.z | vk.w) != 0u) {
                int g   = g0 + k * SCAN_STRIDE;
                int row = g / (N / 4);                 // rare path; magic-mul div
                int cb  = (g - row * (N / 4)) * 4;
                unsigned e[4] = {vk.x, vk.y, vk.z, vk.w};
                #pragma unroll
                for (int c = 0; c < 4; ++c) {
                    if (e[c] != 0u) {
                        int pos = atomicAdd(&cnt[row], 1);
                        if (pos < CAP) cols[row * CAP + pos] = cb + c;
                    }
                }
            }
        }
    }
}

// K2b: per-row gather from the compact lists. kmat/h (3 MB each) are fetched
// once from HBM post-scan, then L3-resident (25x average reuse); 4 waves split
// the ~25 neighbors, LDS combine, Lorentz normalize.
__global__ __launch_bounds__(256) void gather_kernel(
        const int* __restrict__ cnt,
        const int* __restrict__ cols,
        const float* __restrict__ qm,
        const float* __restrict__ kmat,
        const float* __restrict__ h,
        const float* __restrict__ att_bias_p,
        const float* __restrict__ att_scale_p,
        float* __restrict__ out) {
    __shared__ float sacc[4][D];

    const int tid  = threadIdx.x;
    const int row  = blockIdx.x;
    const int lane = tid & 63;
    const int w    = tid >> 6;

    float qv        = qm[row * D + lane];
    float bias      = att_bias_p[0];
    float inv_scale = 1.0f / att_scale_p[0];

    int m = cnt[row]; if (m > CAP) m = CAP;
    const int* cl = cols + row * CAP;

    float acc = 0.0f;
    int n = w;
    int j = (n < m) ? cl[n] : 0;
    for (; n < m; n += 4) {
        int jn = (n + 4 < m) ? cl[n + 4] : 0;      // prefetch next list entry
        float kv = kmat[j * D + lane];
        float hv = h[j * D + lane];
        float dot = wave_sum(qv * kv);
        float att = sigmoidf(fmaf(2.0f + 2.0f * dot, inv_scale, bias));
        acc = fmaf(att, hv, acc);
        j = jn;
    }
    sacc[w][lane] = acc;
    __syncthreads();

    if (w == 0) {
        float total   = sacc[0][lane] + sacc[1][lane] + sacc[2][lane] + sacc[3][lane];
        float contrib = (lane == 0) ? -total * total : total * total;
        float inner   = wave_sum(contrib);
        float denorm  = sqrtf(fmaxf(fabsf(inner), 1e-8f));
        out[row * D + lane] = total / denorm;
    }
}

extern "C" void kernel_launch(void* const* d_in, const int* in_sizes, int n_in,
                              void* d_out, int out_size, void* d_ws, size_t ws_size,
                              hipStream_t stream) {
    const float*  x         = (const float*)d_in[0];
    const uint4n* adj       = (const uint4n*)d_in[1];
    const float*  W         = (const float*)d_in[2];
    const float*  b         = (const float*)d_in[3];
    const float*  scale     = (const float*)d_in[4];
    const float*  Wq        = (const float*)d_in[5];
    const float*  bq        = (const float*)d_in[6];
    const float*  scale_q   = (const float*)d_in[7];
    const float*  Wk        = (const float*)d_in[8];
    const float*  bk        = (const float*)d_in[9];
    const float*  scale_k   = (const float*)d_in[10];
    const float*  att_bias  = (const float*)d_in[11];
    const float*  att_scale = (const float*)d_in[12];
    float* out = (float*)d_out;

    float* h    = (float*)d_ws;                 // N*D f32
    float* qm   = h    + (size_t)N * D;         // N*D f32
    float* kmat = qm   + (size_t)N * D;         // N*D f32
    int*   cnt  = (int*)(kmat + (size_t)N * D); // N i32
    int*   cols = cnt  + N;                     // N*CAP i32  (total ws ~14.2 MB)

    linear_kernel<<<N / 4, 256, 0, stream>>>(x, W, b, scale,
                                             Wq, bq, scale_q, Wk, bk, scale_k,
                                             h, qm, kmat, cnt);
    scan_kernel<<<SCAN_BLOCKS, 256, 0, stream>>>(adj, cnt, cols);
    gather_kernel<<<N, 256, 0, stream>>>(cnt, cols, qm, kmat, h,
                                         att_bias, att_scale, out);
}

// Round 3
// 839.367 us; speedup vs baseline: 1.0413x; 1.0413x over previous
//
#include <hip/hip_runtime.h>
#include <math.h>

#define N   12288
#define D   64
#define CAP 96   // max neighbors/row; Binomial(12288,0.002) mean 24.6, P(>=96) ~ 1e-30
#define ITS ((N / 4) / 256)   // 12 x 16B chunks per thread per row

typedef unsigned int uint4n __attribute__((ext_vector_type(4)));

__device__ __forceinline__ float wave_sum(float v) {
    #pragma unroll
    for (int m = 32; m >= 1; m >>= 1) v += __shfl_xor(v, m, 64);
    return v;
}
__device__ __forceinline__ float sigmoidf(float a) { return 1.0f / (1.0f + __expf(-a)); }

// async 16B global->LDS (DMA path, bypasses VGPR return / L1 allocate).
// LDS dest is wave-uniform base + lane*16 (HW-added); global src is per-lane.
__device__ __forceinline__ void load_lds16(const void* g, void* l) {
    __builtin_amdgcn_global_load_lds(
        (const __attribute__((address_space(1))) unsigned int*)g,
        (__attribute__((address_space(3))) unsigned int*)l, 16, 0, 0);
}

// K1: one wave per row: h = LL(x) kept in registers, then q (negated time) and k
// computed straight from register h. One dispatch for all three linears.
__global__ __launch_bounds__(256) void linear_kernel(
        const float* __restrict__ x,
        const float* __restrict__ W,  const float* __restrict__ b,  const float* __restrict__ scale,
        const float* __restrict__ Wq, const float* __restrict__ bq, const float* __restrict__ scale_q,
        const float* __restrict__ Wk, const float* __restrict__ bk, const float* __restrict__ scale_k,
        float* __restrict__ h, float* __restrict__ qm, float* __restrict__ kmat) {
    __shared__ float Wl [D * (D + 1)];   // +1 pad: 2-way bank alias (free)
    __shared__ float Wql[D * (D + 1)];
    __shared__ float Wkl[D * (D + 1)];

    const int tid  = threadIdx.x;
    const int lane = tid & 63;
    const int w    = tid >> 6;
    const int row  = blockIdx.x * 4 + w;

    for (int idx = tid; idx < D * D; idx += 256) {
        int d = idx >> 6, kk = idx & 63;
        Wl [d * (D + 1) + kk] = W [idx];
        Wql[d * (D + 1) + kk] = Wq[idx];
        Wkl[d * (D + 1) + kk] = Wk[idx];
    }
    __syncthreads();

    float hvv;
    {
        float xv  = x[row * D + lane];
        float acc = b[lane];
        const float* wr = &Wl[lane * (D + 1)];
        #pragma unroll
        for (int kk = 0; kk < D; ++kk)
            acc = fmaf(__shfl(xv, kk, 64), wr[kk], acc);
        float h0   = __shfl(acc, 0, 64);
        float time = __expf(scale[0]) * sigmoidf(h0) + 1.1f;
        float sq   = fmaxf(wave_sum((lane == 0) ? 0.0f : acc * acc), 1e-8f);
        float r    = sqrtf((time * time - 1.0f) / sq);
        hvv = (lane == 0) ? time : acc * r;
        h[row * D + lane] = hvv;
    }

    {
        float accq = bq[lane], acck = bk[lane];
        const float* wq = &Wql[lane * (D + 1)];
        const float* wk = &Wkl[lane * (D + 1)];
        #pragma unroll
        for (int kk = 0; kk < D; ++kk) {
            float xk = __shfl(hvv, kk, 64);
            accq = fmaf(xk, wq[kk], accq);
            acck = fmaf(xk, wk[kk], acck);
        }
        {
            float h0   = __shfl(accq, 0, 64);
            float time = __expf(scale_q[0]) * sigmoidf(h0) + 1.1f;
            float sq   = fmaxf(wave_sum((lane == 0) ? 0.0f : accq * accq), 1e-8f);
            float r    = sqrtf((time * time - 1.0f) / sq);
            qm[row * D + lane] = (lane == 0) ? -time : accq * r;
        }
        {
            float h0   = __shfl(acck, 0, 64);
            float time = __expf(scale_k[0]) * sigmoidf(h0) + 1.1f;
            float sq   = fmaxf(wave_sum((lane == 0) ? 0.0f : acck * acck), 1e-8f);
            float r    = sqrtf((time * time - 1.0f) / sq);
            kmat[row * D + lane] = (lane == 0) ? time : acck * r;
        }
    }
}

// K2 (fused, round-0 structure): block `row` streams adj[row,:] (48 KB) via
// global_load_lds DMA into LDS (bypasses the VGPR load-return path that capped
// every register-staged variant at ~1.6 TB/s), then compacts nonzero cols and
// gathers sigmoid-weighted h rows. The mandatory scnt barrier also drains
// vmcnt(0), so the staged data is visible with no extra waits.
__global__ __launch_bounds__(256) void adj_gather_kernel(
        const float* __restrict__ adj,
        const float* __restrict__ qm,
        const float* __restrict__ kmat,
        const float* __restrict__ h,
        const float* __restrict__ att_bias_p,
        const float* __restrict__ att_scale_p,
        float* __restrict__ out) {
    __shared__ __align__(16) unsigned int sadj[N];   // 48 KB: one full adj row
    __shared__ int scols[CAP];
    __shared__ int scnt;
    __shared__ float sacc[4][D];

    const int tid  = threadIdx.x;
    const int row  = blockIdx.x;
    const int lane = tid & 63;
    const int w    = tid >> 6;
    if (tid == 0) scnt = 0;

    // issue all 12 DMA loads back-to-back; chunk (w*ITS+i)*64+lane is linear
    // on both the global and LDS side (LDS base wave-uniform, +lane*16 by HW)
    const char* rowbase = (const char*)adj + (size_t)row * (size_t)(N * 4);
    #pragma unroll
    for (int i = 0; i < ITS; ++i) {
        const int cbase = (w * ITS + i) * 64;          // wave-uniform
        load_lds16(rowbase + (size_t)(cbase + lane) * 16, (void*)&sadj[cbase * 4]);
    }

    float qv        = qm[row * D + lane];   // overlaps with DMA
    float bias      = att_bias_p[0];
    float inv_scale = 1.0f / att_scale_p[0];
    __syncthreads();   // drains vmcnt(0): sadj ready, scnt=0 visible

    #pragma unroll
    for (int it = 0; it < ITS; ++it) {
        int t = it * 256 + tid;
        uint4n v = *(const uint4n*)&sadj[t * 4];       // ds_read_b128
        if ((v.x | v.y | v.z | v.w) != 0u) {
            unsigned e[4] = {v.x, v.y, v.z, v.w};
            #pragma unroll
            for (int c = 0; c < 4; ++c) {
                if (e[c] != 0u) {
                    int pos = atomicAdd(&scnt, 1);     // LDS atomic, rare (~25/row)
                    if (pos < CAP) scols[pos] = t * 4 + c;
                }
            }
        }
    }
    __syncthreads();

    int m = scnt; if (m > CAP) m = CAP;

    float acc = 0.0f;
    int n = w;
    int j = (n < m) ? scols[n] : 0;
    for (; n < m; n += 4) {
        int jn = (n + 4 < m) ? scols[n + 4] : 0;       // prefetch next list entry
        float kv = kmat[j * D + lane];
        float hv = h[j * D + lane];
        float dot = wave_sum(qv * kv);
        float att = sigmoidf(fmaf(2.0f + 2.0f * dot, inv_scale, bias));
        acc = fmaf(att, hv, acc);
        j = jn;
    }
    sacc[w][lane] = acc;
    __syncthreads();

    if (w == 0) {
        float total   = sacc[0][lane] + sacc[1][lane] + sacc[2][lane] + sacc[3][lane];
        float contrib = (lane == 0) ? -total * total : total * total;
        float inner   = wave_sum(contrib);
        float denorm  = sqrtf(fmaxf(fabsf(inner), 1e-8f));
        out[row * D + lane] = total / denorm;
    }
}

extern "C" void kernel_launch(void* const* d_in, const int* in_sizes, int n_in,
                              void* d_out, int out_size, void* d_ws, size_t ws_size,
                              hipStream_t stream) {
    const float*  x         = (const float*)d_in[0];
    const float*  adj       = (const float*)d_in[1];
    const float*  W         = (const float*)d_in[2];
    const float*  b         = (const float*)d_in[3];
    const float*  scale     = (const float*)d_in[4];
    const float*  Wq        = (const float*)d_in[5];
    const float*  bq        = (const float*)d_in[6];
    const float*  scale_q   = (const float*)d_in[7];
    const float*  Wk        = (const float*)d_in[8];
    const float*  bk        = (const float*)d_in[9];
    const float*  scale_k   = (const float*)d_in[10];
    const float*  att_bias  = (const float*)d_in[11];
    const float*  att_scale = (const float*)d_in[12];
    float* out = (float*)d_out;

    float* h    = (float*)d_ws;           // N*D
    float* qm   = h  + (size_t)N * D;     // N*D
    float* kmat = qm + (size_t)N * D;     // N*D

    linear_kernel<<<N / 4, 256, 0, stream>>>(x, W, b, scale,
                                             Wq, bq, scale_q, Wk, bk, scale_k,
                                             h, qm, kmat);
    adj_gather_kernel<<<N, 256, 0, stream>>>(adj, qm, kmat, h,
                                             att_bias, att_scale, out);
}

// Round 4
// 789.799 us; speedup vs baseline: 1.1066x; 1.0628x over previous
//
#include <hip/hip_runtime.h>
#include <math.h>

#define N   12288
#define D   64
#define CAP 96   // max neighbors/row; Binomial(12288,0.002) mean 24.6, P(>=96) ~ 1e-30
#define ITS ((N / 4) / 256)   // 12 x 16B chunks per thread per row

typedef unsigned int uint4n __attribute__((ext_vector_type(4)));
typedef unsigned int u32x4  __attribute__((ext_vector_type(4)));

__device__ __forceinline__ float wave_sum(float v) {
    #pragma unroll
    for (int m = 32; m >= 1; m >>= 1) v += __shfl_xor(v, m, 64);
    return v;
}
__device__ __forceinline__ float sigmoidf(float a) { return 1.0f / (1.0f + __expf(-a)); }

// System-scope non-temporal 16B read: sc0 sc1 nt bypasses L1/L2/L3 allocation.
// The one cache-path variant not yet tried; NT-builtin (nt only) still allocates.
// NOTE: asm loads are not vmcnt-tracked by the compiler — caller must fence
// with an explicit s_waitcnt vmcnt(0) before consuming.
__device__ __forceinline__ uint4n adj_load16(u32x4 srsrc, int voff) {
    uint4n d;
    asm volatile("buffer_load_dwordx4 %0, %1, %2, 0 offen sc0 sc1 nt"
                 : "=v"(d)
                 : "v"(voff), "s"(srsrc));
    return d;
}

// K1: one wave per row: h = LL(x) kept in registers, then q (negated time) and k
// computed straight from register h. One dispatch for all three linears.
__global__ __launch_bounds__(256) void linear_kernel(
        const float* __restrict__ x,
        const float* __restrict__ W,  const float* __restrict__ b,  const float* __restrict__ scale,
        const float* __restrict__ Wq, const float* __restrict__ bq, const float* __restrict__ scale_q,
        const float* __restrict__ Wk, const float* __restrict__ bk, const float* __restrict__ scale_k,
        float* __restrict__ h, float* __restrict__ qm, float* __restrict__ kmat) {
    __shared__ float Wl [D * (D + 1)];   // +1 pad: 2-way bank alias (free)
    __shared__ float Wql[D * (D + 1)];
    __shared__ float Wkl[D * (D + 1)];

    const int tid  = threadIdx.x;
    const int lane = tid & 63;
    const int w    = tid >> 6;
    const int row  = blockIdx.x * 4 + w;

    for (int idx = tid; idx < D * D; idx += 256) {
        int d = idx >> 6, kk = idx & 63;
        Wl [d * (D + 1) + kk] = W [idx];
        Wql[d * (D + 1) + kk] = Wq[idx];
        Wkl[d * (D + 1) + kk] = Wk[idx];
    }
    __syncthreads();

    float hvv;
    {
        float xv  = x[row * D + lane];
        float acc = b[lane];
        const float* wr = &Wl[lane * (D + 1)];
        #pragma unroll
        for (int kk = 0; kk < D; ++kk)
            acc = fmaf(__shfl(xv, kk, 64), wr[kk], acc);
        float h0   = __shfl(acc, 0, 64);
        float time = __expf(scale[0]) * sigmoidf(h0) + 1.1f;
        float sq   = fmaxf(wave_sum((lane == 0) ? 0.0f : acc * acc), 1e-8f);
        float r    = sqrtf((time * time - 1.0f) / sq);
        hvv = (lane == 0) ? time : acc * r;
        h[row * D + lane] = hvv;
    }

    {
        float accq = bq[lane], acck = bk[lane];
        const float* wq = &Wql[lane * (D + 1)];
        const float* wk = &Wkl[lane * (D + 1)];
        #pragma unroll
        for (int kk = 0; kk < D; ++kk) {
            float xk = __shfl(hvv, kk, 64);
            accq = fmaf(xk, wq[kk], accq);
            acck = fmaf(xk, wk[kk], acck);
        }
        {
            float h0   = __shfl(accq, 0, 64);
            float time = __expf(scale_q[0]) * sigmoidf(h0) + 1.1f;
            float sq   = fmaxf(wave_sum((lane == 0) ? 0.0f : accq * accq), 1e-8f);
            float r    = sqrtf((time * time - 1.0f) / sq);
            qm[row * D + lane] = (lane == 0) ? -time : accq * r;
        }
        {
            float h0   = __shfl(acck, 0, 64);
            float time = __expf(scale_k[0]) * sigmoidf(h0) + 1.1f;
            float sq   = fmaxf(wave_sum((lane == 0) ? 0.0f : acck * acck), 1e-8f);
            float r    = sqrtf((time * time - 1.0f) / sq);
            kmat[row * D + lane] = (lane == 0) ? time : acck * r;
        }
    }
}

// K2 (R0 fused structure, single change: adj reads via buffer_load sc0 sc1 nt).
// Block `row` streams adj[row,:] (48 KB) with all 12 16B loads issued
// back-to-back into registers, then compacts nonzero cols to LDS and gathers
// sigmoid-weighted h rows.
__global__ __launch_bounds__(256) void adj_gather_kernel(
        const void* __restrict__ adj,
        const float* __restrict__ qm,
        const float* __restrict__ kmat,
        const float* __restrict__ h,
        const float* __restrict__ att_bias_p,
        const float* __restrict__ att_scale_p,
        float* __restrict__ out) {
    __shared__ int scols[CAP];
    __shared__ int scnt;
    __shared__ float sacc[4][D];

    const int tid  = threadIdx.x;
    const int row  = blockIdx.x;
    const int lane = tid & 63;
    const int w    = tid >> 6;
    if (tid == 0) scnt = 0;

    // SRSRC bounding this block's 48 KB row; voffset = chunk*16 within the row
    const unsigned long long rowbase =
        (unsigned long long)adj + (unsigned long long)row * (unsigned)(N * 4);
    u32x4 srsrc;
    srsrc.x = (unsigned)rowbase;
    srsrc.y = (unsigned)(rowbase >> 32) & 0xFFFFu;   // base[47:32], stride=0
    srsrc.z = (unsigned)(N * 4);                     // num_records (bytes)
    srsrc.w = 0x00020000u;                           // raw dword access

    uint4n vv[ITS];
    #pragma unroll
    for (int it = 0; it < ITS; ++it)
        vv[it] = adj_load16(srsrc, (it * 256 + tid) * 16);

    float qv        = qm[row * D + lane];   // overlaps with stream
    float bias      = att_bias_p[0];
    float inv_scale = 1.0f / att_scale_p[0];
    asm volatile("s_waitcnt vmcnt(0)" ::: "memory");   // asm loads are untracked
    __syncthreads();   // scnt=0 visible

    #pragma unroll
    for (int it = 0; it < ITS; ++it) {
        uint4n v = vv[it];
        if ((v.x | v.y | v.z | v.w) != 0u) {
            int t = it * 256 + tid;
            unsigned e[4] = {v.x, v.y, v.z, v.w};
            #pragma unroll
            for (int c = 0; c < 4; ++c) {
                if (e[c] != 0u) {
                    int pos = atomicAdd(&scnt, 1);   // LDS atomic, rare (~25/row)
                    if (pos < CAP) scols[pos] = t * 4 + c;
                }
            }
        }
    }
    __syncthreads();

    int m = scnt; if (m > CAP) m = CAP;

    float acc = 0.0f;
    for (int n = w; n < m; n += 4) {
        int j = scols[n];                                  // wave-uniform broadcast
        float dot = wave_sum(qv * kmat[j * D + lane]);
        float att = sigmoidf(fmaf(2.0f + 2.0f * dot, inv_scale, bias));
        acc = fmaf(att, h[j * D + lane], acc);
    }
    sacc[w][lane] = acc;
    __syncthreads();

    if (w == 0) {
        float total   = sacc[0][lane] + sacc[1][lane] + sacc[2][lane] + sacc[3][lane];
        float contrib = (lane == 0) ? -total * total : total * total;
        float inner   = wave_sum(contrib);
        float denorm  = sqrtf(fmaxf(fabsf(inner), 1e-8f));
        out[row * D + lane] = total / denorm;
    }
}

extern "C" void kernel_launch(void* const* d_in, const int* in_sizes, int n_in,
                              void* d_out, int out_size, void* d_ws, size_t ws_size,
                              hipStream_t stream) {
    const float*  x         = (const float*)d_in[0];
    const void*   adj       = (const void*)d_in[1];
    const float*  W         = (const float*)d_in[2];
    const float*  b         = (const float*)d_in[3];
    const float*  scale     = (const float*)d_in[4];
    const float*  Wq        = (const float*)d_in[5];
    const float*  bq        = (const float*)d_in[6];
    const float*  scale_q   = (const float*)d_in[7];
    const float*  Wk        = (const float*)d_in[8];
    const float*  bk        = (const float*)d_in[9];
    const float*  scale_k   = (const float*)d_in[10];
    const float*  att_bias  = (const float*)d_in[11];
    const float*  att_scale = (const float*)d_in[12];
    float* out = (float*)d_out;

    float* h    = (float*)d_ws;           // N*D
    float* qm   = h  + (size_t)N * D;     // N*D
    float* kmat = qm + (size_t)N * D;     // N*D

    linear_kernel<<<N / 4, 256, 0, stream>>>(x, W, b, scale,
                                             Wq, bq, scale_q, Wk, bk, scale_k,
                                             h, qm, kmat);
    adj_gather_kernel<<<N, 256, 0, stream>>>(adj, qm, kmat, h,
                                             att_bias, att_scale, out);
}